// Round 6
// baseline (144.946 us; speedup 1.0000x reference)
//
#include <hip/hip_runtime.h>
#include <hip/hip_bf16.h>
#include <cstdint>
#include <cstddef>

// SelfAttention fused block, MI355X gfx950.
// Round 5: QKV GEMM -> 256x256 8-phase counted-vmcnt schedule (T2+T3+T4+T5).
//  - BK=64, 512 thr (8 waves 2Mx4N), per-wave C = 128x64, LDS 128KB dbuf.
//  - Staging unit = K-half (A or B x 32-k-cols, 16KB, 2 gload_lds/thread).
//    Phase p consumes halves staged 3 phases earlier; vmcnt(4) before the
//    trailing barrier of phases 2&4 retires exactly the 2 halves needed next.
//  - XOR swizzle chunk^=(row&3) on both stage-source and ds_read (rule 21).
//  - raw s_barrier (no vmcnt(0) drain), lgkmcnt(0), setprio around MFMA.
//  - XCD-bijective grid swizzle (192 = 8*24).
// Attn (round-4 version) and out-proj GEMM unchanged.

using bf16 = __hip_bfloat16;
typedef __attribute__((ext_vector_type(8))) short short8;
typedef __attribute__((ext_vector_type(4))) float f32x4;
typedef __attribute__((ext_vector_type(16))) float f32x16;
typedef __attribute__((ext_vector_type(4))) unsigned int u32x4;

__device__ __forceinline__ unsigned short f2b(float f) {
    bf16 h = __float2bfloat16(f);
    return *reinterpret_cast<unsigned short*>(&h);
}

__device__ __forceinline__ void async16(const void* g, void* l) {
    __builtin_amdgcn_global_load_lds(
        (const __attribute__((address_space(1))) void*)g,
        (__attribute__((address_space(3))) void*)l, 16, 0, 0);
}

// ---------------- K1: fp32 -> bf16 elementwise (float4 / ushort4) ------------
__global__ __launch_bounds__(256) void cvt_kernel(const float* __restrict__ in,
                                                  bf16* __restrict__ out, int n4) {
    int i = blockIdx.x * 256 + threadIdx.x;
    if (i >= n4) return;
    const float4 v = reinterpret_cast<const float4*>(in)[i];
    ushort4 o;
    o.x = f2b(v.x); o.y = f2b(v.y); o.z = f2b(v.z); o.w = f2b(v.w);
    reinterpret_cast<ushort4*>(out)[i] = o;
}

// ---------------- K2: in fp32 [K][N] -> out bf16 [N][K] ----------------------
__global__ __launch_bounds__(256) void transpose_cvt(const float* __restrict__ in,
                                                     bf16* __restrict__ out,
                                                     int K, int N) {
    __shared__ float tile[32][33];
    int n0 = blockIdx.x * 32, k0 = blockIdx.y * 32;
    int tx = threadIdx.x, ty = threadIdx.y;  // (32,8)
    #pragma unroll
    for (int i = 0; i < 32; i += 8)
        tile[ty + i][tx] = in[(size_t)(k0 + ty + i) * N + n0 + tx];
    __syncthreads();
    #pragma unroll
    for (int i = 0; i < 32; i += 8)
        out[(size_t)(n0 + ty + i) * K + k0 + tx] = __float2bfloat16(tile[tx][ty + i]);
}

// ---------------- K3: QKV projection, 256^2 8-phase --------------------------
#define BAR __builtin_amdgcn_s_barrier()
#define LGKM0 asm volatile("s_waitcnt lgkmcnt(0)" ::: "memory")
#define VM4 asm volatile("s_waitcnt vmcnt(4)" ::: "memory")
#define VM0 asm volatile("s_waitcnt vmcnt(0)" ::: "memory")
#define PRIO1 __builtin_amdgcn_s_setprio(1)
#define PRIO0 __builtin_amdgcn_s_setprio(0)

#define PH_READ_A(D, KS, MO)                                              \
    {                                                                     \
        _Pragma("unroll") for (int mi = 0; mi < 4; ++mi)                  \
            af[mi] = *reinterpret_cast<const short8*>(                    \
                &As[D][KS][(arow0 + ((MO) + mi) * 16) * 32 + swz]);       \
    }
#define PH_READ_B(D, KS)                                                  \
    {                                                                     \
        _Pragma("unroll") for (int ni = 0; ni < 4; ++ni)                  \
            bfv[ni] = *reinterpret_cast<const short8*>(                   \
                &Bs[D][KS][(brow0 + ni * 16) * 32 + swz]);                \
    }
#define MFMA16(MO)                                                        \
    {                                                                     \
        _Pragma("unroll") for (int mi = 0; mi < 4; ++mi) {                \
            _Pragma("unroll") for (int ni = 0; ni < 4; ++ni) {            \
                acc[(MO) + mi][ni] = __builtin_amdgcn_mfma_f32_16x16x32_bf16( \
                    af[mi], bfv[ni], acc[(MO) + mi][ni], 0, 0, 0);        \
            }                                                             \
        }                                                                 \
    }

__global__ __launch_bounds__(512, 2) void gemm_qkv_8ph(
    const bf16* __restrict__ A,   // [4096][1024] bf16 (x)
    const bf16* __restrict__ Bt,  // [3072][1024] bf16 (Wqkv^T)
    const float* __restrict__ bias,
    bf16* __restrict__ qd, bf16* __restrict__ kd, bf16* __restrict__ vtd) {
    constexpr int Kd = 1024;
    constexpr int NT = Kd / 64;  // 16 K-tiles
    __shared__ bf16 As[2][2][256 * 32];  // [dbuf][k-half][row*32 + swz-col]
    __shared__ bf16 Bs[2][2][256 * 32];

    const int tid = threadIdx.x;
    const int wave = tid >> 6, lane = tid & 63;
    const int lr = lane & 15, lg = lane >> 4;
    const int wr = wave >> 2, wc = wave & 3;  // 2 x 4 waves

    // XCD-bijective swizzle: 192 blocks = 8 XCDs x 24
    const int orig = blockIdx.x;
    const int wg = (orig & 7) * 24 + (orig >> 3);
    const int bx = wg / 12, by = wg % 12;
    const int m0 = bx * 256, n0 = by * 256;

    // staging source coords: inst j covers LDS bytes p = j*8192 + tid*16
    int s_row[2], s_col[2];
    #pragma unroll
    for (int j = 0; j < 2; ++j) {
        const int p = j * 8192 + tid * 16;
        const int row = p >> 6;
        const int c = ((p >> 4) & 3) ^ (row & 3);
        s_row[j] = row;
        s_col[j] = c * 8;
    }

    auto stageA = [&](int d, int ks, int kt) {
        const int kb = kt * 64 + ks * 32;
        #pragma unroll
        for (int j = 0; j < 2; ++j)
            async16(A + (size_t)(m0 + s_row[j]) * Kd + kb + s_col[j],
                    &As[d][ks][j * 4096 + tid * 8]);
    };
    auto stageB = [&](int d, int ks, int kt) {
        const int kb = kt * 64 + ks * 32;
        #pragma unroll
        for (int j = 0; j < 2; ++j)
            async16(Bt + (size_t)(n0 + s_row[j]) * Kd + kb + s_col[j],
                    &Bs[d][ks][j * 4096 + tid * 8]);
    };

    const int swz = (lg ^ (lr & 3)) * 8;  // read-side XOR (rows: &3 == lr&3)
    const int arow0 = wr * 128 + lr;
    const int brow0 = wc * 64 + lr;

    f32x4 acc[8][4] = {};
    short8 af[4], bfv[4];

    // ---- prologue: stage tile 0 (A0,B0,A1,B1), wait first two halves ----
    stageA(0, 0, 0);
    stageB(0, 0, 0);
    stageA(0, 1, 0);
    stageB(0, 1, 0);
    VM4;
    BAR;

    for (int kt = 0; kt < NT - 1; ++kt) {
        const int d = kt & 1;
        const int kn = kt + 1;
        // phase 1: G0 x ks0; stage A0(kn)
        PH_READ_B(d, 0);
        PH_READ_A(d, 0, 0);
        stageA(d ^ 1, 0, kn);
        BAR; LGKM0; PRIO1; MFMA16(0); PRIO0; BAR;
        // phase 2: G1 x ks0; stage B0(kn); vmcnt(4) retires A1,B1(kt)
        PH_READ_A(d, 0, 4);
        stageB(d ^ 1, 0, kn);
        BAR; LGKM0; PRIO1; MFMA16(4); PRIO0; VM4; BAR;
        // phase 3: G0 x ks1; stage A1(kn)
        PH_READ_B(d, 1);
        PH_READ_A(d, 1, 0);
        stageA(d ^ 1, 1, kn);
        BAR; LGKM0; PRIO1; MFMA16(0); PRIO0; BAR;
        // phase 4: G1 x ks1; stage B1(kn); vmcnt(4) retires A0,B0(kn)
        PH_READ_A(d, 1, 4);
        stageB(d ^ 1, 1, kn);
        BAR; LGKM0; PRIO1; MFMA16(4); PRIO0; VM4; BAR;
    }
    {   // ---- last tile (d = 1), no staging; drain remaining halves ----
        PH_READ_B(1, 0);
        PH_READ_A(1, 0, 0);
        BAR; LGKM0; PRIO1; MFMA16(0); PRIO0; BAR;
        PH_READ_A(1, 0, 4);
        BAR; LGKM0; PRIO1; MFMA16(4); PRIO0; VM0; BAR;
        PH_READ_B(1, 1);
        PH_READ_A(1, 1, 0);
        BAR; LGKM0; PRIO1; MFMA16(0); PRIO0; BAR;
        PH_READ_A(1, 1, 4);
        BAR; LGKM0; PRIO1; MFMA16(4); PRIO0;
    }

    // ---- epilogue: bias + scatter to q,k [B,H,S,dh] / v^T [B,H,dh,S] ----
    #pragma unroll
    for (int mi = 0; mi < 8; ++mi) {
        #pragma unroll
        for (int ni = 0; ni < 4; ++ni) {
            #pragma unroll
            for (int r = 0; r < 4; ++r) {
                const int row = m0 + wr * 128 + mi * 16 + lg * 4 + r;
                const int col = n0 + wc * 64 + ni * 16 + lr;
                const float v = acc[mi][ni][r] + bias[col];
                const bf16 hv = __float2bfloat16(v);
                const int part = col >> 10;      // 0=q 1=k 2=v
                const int within = col & 1023;
                const int h = within >> 6, dd = within & 63;
                const int b = row >> 11, s = row & 2047;
                const int bh = b * 16 + h;
                if (part == 0)
                    qd[((size_t)bh * 2048 + s) * 64 + dd] = hv;
                else if (part == 1)
                    kd[((size_t)bh * 2048 + s) * 64 + dd] = hv;
                else
                    vtd[((size_t)bh * 64 + dd) * 2048 + s] = hv;
            }
        }
    }
}

// ---------------- K5: 128x128x32 bf16 MFMA GEMM, B^T input (out proj) --------
template <int EPI>
__global__ __launch_bounds__(256) void gemm_bt(
    const bf16* __restrict__ A,   // [M][K] bf16
    const bf16* __restrict__ Bt,  // [N][K] bf16
    const float* __restrict__ bias,  // [N] fp32
    float* __restrict__ Cf,          // [M][N] fp32
    int M, int N, int K) {
    __shared__ bf16 As[128 * 32];
    __shared__ bf16 Bs[128 * 32];
    const int t = threadIdx.x;
    const int lane = t & 63;
    const int lr = lane & 15, lg = lane >> 4;
    const int wave = t >> 6;
    const int wr = wave >> 1, wc = wave & 1;  // 2x2 waves of 64x64
    const int m0 = blockIdx.x * 128, n0 = blockIdx.y * 128;

    const bf16* aSrc = A + (size_t)(m0 + (t >> 2)) * K + (t & 3) * 8;
    const bf16* bSrc = Bt + (size_t)(n0 + (t >> 2)) * K + (t & 3) * 8;
    bf16* aDst0 = &As[t * 8];
    bf16* aDst1 = &As[2048 + t * 8];
    bf16* bDst0 = &Bs[t * 8];
    bf16* bDst1 = &Bs[2048 + t * 8];
    const size_t rowStep = (size_t)64 * K;

    f32x4 acc[4][4] = {};

    for (int k0 = 0; k0 < K; k0 += 32) {
        __syncthreads();
        async16(aSrc + k0, aDst0);
        async16(aSrc + rowStep + k0, aDst1);
        async16(bSrc + k0, bDst0);
        async16(bSrc + rowStep + k0, bDst1);
        __syncthreads();
        short8 af[4], bfr[4];
        #pragma unroll
        for (int i = 0; i < 4; ++i)
            af[i] = *reinterpret_cast<const short8*>(
                &As[(wr * 64 + i * 16 + lr) * 32 + lg * 8]);
        #pragma unroll
        for (int i = 0; i < 4; ++i)
            bfr[i] = *reinterpret_cast<const short8*>(
                &Bs[(wc * 64 + i * 16 + lr) * 32 + lg * 8]);
        #pragma unroll
        for (int mi = 0; mi < 4; ++mi)
            #pragma unroll
            for (int ni = 0; ni < 4; ++ni)
                acc[mi][ni] = __builtin_amdgcn_mfma_f32_16x16x32_bf16(
                    af[mi], bfr[ni], acc[mi][ni], 0, 0, 0);
    }

    #pragma unroll
    for (int mi = 0; mi < 4; ++mi) {
        #pragma unroll
        for (int ni = 0; ni < 4; ++ni) {
            #pragma unroll
            for (int r = 0; r < 4; ++r) {
                const int row = m0 + wr * 64 + mi * 16 + lg * 4 + r;
                const int col = n0 + wc * 64 + ni * 16 + lr;
                Cf[(size_t)row * N + col] = acc[mi][ni][r] + bias[col];
            }
        }
    }
}

// ---------------- K4: causal flash attention (round-4 version) ---------------
__global__ __launch_bounds__(256, 2) void attn_kernel(const bf16* __restrict__ q,
                                                      const bf16* __restrict__ k,
                                                      const bf16* __restrict__ vt,
                                                      bf16* __restrict__ o) {
    const int S = 2048;
    const int f = blockIdx.x;
    const int res = f & 7, m = f >> 3;
    const int grp = m >> 4;
    const int bh = res + 8 * grp;
    const int bxr = m & 15;
    const int bx = (grp & 2) ? (15 - bxr) : bxr;
    const int b = bh >> 4, h = bh & 15;
    const int w = threadIdx.x >> 6;
    const int u = w >> 1, par = w & 1;
    const int lane = threadIdx.x & 63;
    const int ln = lane & 31;
    const int hi = lane >> 5;
    const int P = 2 * (15 - bx) + u;     // 0..31
    const int qbaseA = P * 64;
    const int qbaseB = P * 64 + 32;

    const bf16* qp = q + (size_t)bh * S * 64;
    const bf16* kp = k + (size_t)bh * S * 64;
    const bf16* vp = vt + (size_t)bh * 64 * S;

    short8 qfA[4], qfB[4];
    #pragma unroll
    for (int i = 0; i < 4; ++i) {
        qfA[i] = *reinterpret_cast<const short8*>(
            &qp[(size_t)(qbaseA + ln) * 64 + i * 16 + hi * 8]);
        qfB[i] = *reinterpret_cast<const short8*>(
            &qp[(size_t)(qbaseB + ln) * 64 + i * 16 + hi * 8]);
    }

    f32x16 oA0 = {}, oA1 = {}, oB0 = {}, oB1 = {};
    f32x4 lsvA = {0.f, 0.f, 0.f, 0.f}, lsvB = {0.f, 0.f, 0.f, 0.f};

    short8 kA[4], kB[4], vA[4], vB[4];

    auto kload = [&](short8 (&kf)[4], int tile) {
        const bf16* base = &kp[(size_t)(tile * 32 + ln) * 64 + hi * 8];
        #pragma unroll
        for (int i = 0; i < 4; ++i)
            kf[i] = *reinterpret_cast<const short8*>(base + i * 16);
    };
    auto vload = [&](short8 (&vf)[4], int tile) {
        #pragma unroll
        for (int dblk = 0; dblk < 2; ++dblk)
            #pragma unroll
            for (int half = 0; half < 2; ++half)
                vf[dblk * 2 + half] = *reinterpret_cast<const short8*>(
                    &vp[(size_t)(dblk * 32 + ln) * S + tile * 32 + half * 16 +
                        hi * 8]);
    };

    auto body = [&](const short8 (&kf)[4], const short8 (&vf)[4],
                    const short8 (&qf)[4], f32x16& o0, f32x16& o1, f32x4& lsv,
                    bool diag) {
        f32x16 z0 = {}, z1 = {};
        z0 = __builtin_amdgcn_mfma_f32_32x32x16_bf16(kf[0], qf[0], z0, 0, 0, 0);
        z0 = __builtin_amdgcn_mfma_f32_32x32x16_bf16(kf[1], qf[1], z0, 0, 0, 0);
        z1 = __builtin_amdgcn_mfma_f32_32x32x16_bf16(kf[2], qf[2], z1, 0, 0, 0);
        z1 = __builtin_amdgcn_mfma_f32_32x32x16_bf16(kf[3], qf[3], z1, 0, 0, 0);
        const f32x16 z = z0 + z1;
        f32x16 pv;
        #pragma unroll
        for (int r = 0; r < 16; ++r) {
            const int kreg = (r & 3) + 8 * (r >> 2) + 4 * hi;
            float e = __expf(z[r] * 0.125f);
            if (diag && (kreg > ln)) e = 0.f;
            pv[r] = e;
            lsv[r & 3] += e;
        }
        unsigned a0, a1, b0, b1, c0, c1, d0, d1;
        asm("v_cvt_pk_bf16_f32 %0, %1, %2" : "=v"(a0) : "v"(pv[0]), "v"(pv[1]));
        asm("v_cvt_pk_bf16_f32 %0, %1, %2" : "=v"(a1) : "v"(pv[2]), "v"(pv[3]));
        asm("v_cvt_pk_bf16_f32 %0, %1, %2" : "=v"(b0) : "v"(pv[4]), "v"(pv[5]));
        asm("v_cvt_pk_bf16_f32 %0, %1, %2" : "=v"(b1) : "v"(pv[6]), "v"(pv[7]));
        asm("v_cvt_pk_bf16_f32 %0, %1, %2" : "=v"(c0) : "v"(pv[8]), "v"(pv[9]));
        asm("v_cvt_pk_bf16_f32 %0, %1, %2" : "=v"(c1) : "v"(pv[10]), "v"(pv[11]));
        asm("v_cvt_pk_bf16_f32 %0, %1, %2" : "=v"(d0) : "v"(pv[12]), "v"(pv[13]));
        asm("v_cvt_pk_bf16_f32 %0, %1, %2" : "=v"(d1) : "v"(pv[14]), "v"(pv[15]));
        asm("v_permlane32_swap_b32 %0, %1" : "+v"(a0), "+v"(b0));
        asm("v_permlane32_swap_b32 %0, %1" : "+v"(a1), "+v"(b1));
        asm("v_permlane32_swap_b32 %0, %1" : "+v"(c0), "+v"(d0));
        asm("v_permlane32_swap_b32 %0, %1" : "+v"(c1), "+v"(d1));
        u32x4 t0, t1;
        t0[0] = a0; t0[1] = a1; t0[2] = b0; t0[3] = b1;   // P[q][kv 0..15]
        t1[0] = c0; t1[1] = c1; t1[2] = d0; t1[3] = d1;   // P[q][kv 16..31]
        const short8 pa0 = __builtin_bit_cast(short8, t0);
        const short8 pa1 = __builtin_bit_cast(short8, t1);
        o0 = __builtin_amdgcn_mfma_f32_32x32x16_bf16(pa0, vf[0], o0, 0, 0, 0);
        o0 = __builtin_amdgcn_mfma_f32_32x32x16_bf16(pa1, vf[1], o0, 0, 0, 0);
        o1 = __builtin_amdgcn_mfma_f32_32x32x16_bf16(pa0, vf[2], o1, 0, 0, 0);
        o1 = __builtin_amdgcn_mfma_f32_32x32x16_bf16(pa1, vf[3], o1, 0, 0, 0);
    };

    auto dual = [&](const short8 (&kf)[4], const short8 (&vf)[4]) {
        body(kf, vf, qfA, oA0, oA1, lsvA, false);
        body(kf, vf, qfB, oB0, oB1, lsvB, false);
    };
    auto final_body = [&](const short8 (&kf)[4], const short8 (&vf)[4]) {
        if (par == 0) {
            body(kf, vf, qfA, oA0, oA1, lsvA, true);
            body(kf, vf, qfB, oB0, oB1, lsvB, false);
        } else {
            body(kf, vf, qfB, oB0, oB1, lsvB, true);
        }
    };

    kload(kA, par);
    vload(vA, par);
    int i = 0;
    for (; i + 2 <= P; i += 2) {
        kload(kB, par + 2 * (i + 1));
        vload(vB, par + 2 * (i + 1));
        dual(kA, vA);
        kload(kA, par + 2 * (i + 2));
        vload(vA, par + 2 * (i + 2));
        dual(kB, vB);
    }
    if (i < P) {
        kload(kB, par + 2 * P);
        vload(vB, par + 2 * P);
        dual(kA, vA);
        final_body(kB, vB);
    } else {
        final_body(kA, vA);
    }

    float lsA = (lsvA[0] + lsvA[1]) + (lsvA[2] + lsvA[3]);
    float lsB = (lsvB[0] + lsvB[1]) + (lsvB[2] + lsvB[3]);

    __shared__ float red[2][64][65];
    __shared__ float redl[2][64][2];
    if (par == 1) {
        float* dst = red[u][lane];
        #pragma unroll
        for (int r = 0; r < 16; ++r) {
            dst[r] = oA0[r];
            dst[16 + r] = oA1[r];
            dst[32 + r] = oB0[r];
            dst[48 + r] = oB1[r];
        }
        redl[u][lane][0] = lsA;
        redl[u][lane][1] = lsB;
    }
    __syncthreads();
    if (par == 1) return;
    {
        const float* src = red[u][lane];
        #pragma unroll
        for (int r = 0; r < 16; ++r) {
            oA0[r] += src[r];
            oA1[r] += src[16 + r];
            oB0[r] += src[32 + r];
            oB1[r] += src[48 + r];
        }
        lsA += redl[u][lane][0];
        lsB += redl[u][lane][1];
    }

    lsA += __shfl_xor(lsA, 32, 64);
    lsB += __shfl_xor(lsB, 32, 64);
    const float myInvA = 1.0f / lsA;
    const float myInvB = 1.0f / lsB;
    #pragma unroll
    for (int r = 0; r < 16; ++r) {
        const int qrow = (r & 3) + 8 * (r >> 2) + 4 * hi;
        const float invA = __shfl(myInvA, qrow, 64);
        const float invB = __shfl(myInvB, qrow, 64);
        const size_t rowA = ((size_t)b * S + qbaseA + qrow) * 1024 + h * 64;
        const size_t rowB = ((size_t)b * S + qbaseB + qrow) * 1024 + h * 64;
        o[rowA + ln] = __float2bfloat16(oA0[r] * invA);
        o[rowA + 32 + ln] = __float2bfloat16(oA1[r] * invA);
        o[rowB + ln] = __float2bfloat16(oB0[r] * invB);
        o[rowB + 32 + ln] = __float2bfloat16(oB1[r] * invB);
    }
}

// -----------------------------------------------------------------------------
extern "C" void kernel_launch(void* const* d_in, const int* in_sizes, int n_in,
                              void* d_out, int out_size, void* d_ws, size_t ws_size,
                              hipStream_t stream) {
    const float* x = (const float*)d_in[0];     // [2,2048,1024]
    const float* Wqkv = (const float*)d_in[1];  // [1024,3072]
    const float* bqkv = (const float*)d_in[2];  // [3072]
    const float* Wo = (const float*)d_in[3];    // [1024,1024]
    const float* bo = (const float*)d_in[4];    // [1024]
    float* out = (float*)d_out;                 // [2,2048,1024] fp32
    char* ws = (char*)d_ws;

    // workspace layout (bytes), total 40 MB
    bf16* x_bf = (bf16*)(ws);                  //  8388608  [4096][1024]
    bf16* wqkv_t = (bf16*)(ws + 8388608);      //  6291456  [3072][1024]
    bf16* wo_t = (bf16*)(ws + 14680064);       //  2097152  [1024][1024]
    bf16* qb = (bf16*)(ws + 16777216);         //  8388608  [2,16,2048,64]
    bf16* kb = (bf16*)(ws + 25165824);         //  8388608  [2,16,2048,64]
    bf16* vtb = (bf16*)(ws + 33554432);        //  8388608  [2,16,64,2048]
    bf16* attn_o = x_bf;                       // alias: x_bf dead after gemm1

    cvt_kernel<<<4096, 256, 0, stream>>>(x, x_bf, 1048576);
    transpose_cvt<<<dim3(96, 32), dim3(32, 8), 0, stream>>>(Wqkv, wqkv_t, 1024, 3072);
    transpose_cvt<<<dim3(32, 32), dim3(32, 8), 0, stream>>>(Wo, wo_t, 1024, 1024);
    gemm_qkv_8ph<<<192, 512, 0, stream>>>(x_bf, wqkv_t, bqkv, qb, kb, vtb);
    attn_kernel<<<512, 256, 0, stream>>>(qb, kb, vtb, attn_o);
    gemm_bt<0><<<dim3(32, 8), 256, 0, stream>>>(attn_o, wo_t, bo, out,
                                                4096, 1024, 1024);
}

// Round 7
// 129.053 us; speedup vs baseline: 1.1232x; 1.1232x over previous
//
#include <hip/hip_runtime.h>
#include <hip/hip_bf16.h>
#include <cstdint>
#include <cstddef>

// SelfAttention fused block, MI355X gfx950.
// Round 6: revert QKV to 128x128 2-barrier structure (right tile size for a
// 768-block grid) and fix its LDS bank conflicts properly:
//  - BK=64 LDS layout [128 rows][64 k] (128B rows, 8 x 16B chunks).
//  - XOR swizzle chunk ^= (row&7) as an involution on BOTH sides:
//    inverse-swizzled global_load_lds SOURCE (LDS dest linear, rule 21) and
//    swizzled ds_read_b128 address. Per-read slot distribution is uniform
//    (8 lanes on each of 8 slots = b128 floor) -> conflict-free.
//  - 2 barriers per 64-K (half the old rate); staging insts/K unchanged.
// Unified template for QKV (EPI=1 scatter) and out-proj (EPI=0 fp32+bias).
// Attn (round-4/5 version) unchanged.

using bf16 = __hip_bfloat16;
typedef __attribute__((ext_vector_type(8))) short short8;
typedef __attribute__((ext_vector_type(4))) float f32x4;
typedef __attribute__((ext_vector_type(16))) float f32x16;
typedef __attribute__((ext_vector_type(4))) unsigned int u32x4;

__device__ __forceinline__ unsigned short f2b(float f) {
    bf16 h = __float2bfloat16(f);
    return *reinterpret_cast<unsigned short*>(&h);
}

__device__ __forceinline__ void async16(const void* g, void* l) {
    __builtin_amdgcn_global_load_lds(
        (const __attribute__((address_space(1))) void*)g,
        (__attribute__((address_space(3))) void*)l, 16, 0, 0);
}

// ---------------- K1: fp32 -> bf16 elementwise (float4 / ushort4) ------------
__global__ __launch_bounds__(256) void cvt_kernel(const float* __restrict__ in,
                                                  bf16* __restrict__ out, int n4) {
    int i = blockIdx.x * 256 + threadIdx.x;
    if (i >= n4) return;
    const float4 v = reinterpret_cast<const float4*>(in)[i];
    ushort4 o;
    o.x = f2b(v.x); o.y = f2b(v.y); o.z = f2b(v.z); o.w = f2b(v.w);
    reinterpret_cast<ushort4*>(out)[i] = o;
}

// ---------------- K2: in fp32 [K][N] -> out bf16 [N][K] ----------------------
__global__ __launch_bounds__(256) void transpose_cvt(const float* __restrict__ in,
                                                     bf16* __restrict__ out,
                                                     int K, int N) {
    __shared__ float tile[32][33];
    int n0 = blockIdx.x * 32, k0 = blockIdx.y * 32;
    int tx = threadIdx.x, ty = threadIdx.y;  // (32,8)
    #pragma unroll
    for (int i = 0; i < 32; i += 8)
        tile[ty + i][tx] = in[(size_t)(k0 + ty + i) * N + n0 + tx];
    __syncthreads();
    #pragma unroll
    for (int i = 0; i < 32; i += 8)
        out[(size_t)(n0 + ty + i) * K + k0 + tx] = __float2bfloat16(tile[tx][ty + i]);
}

// ------- K3/K5: 128x128 BK=64 swizzled-LDS bf16 MFMA GEMM, B^T input ---------
// EPI==0: C fp32 = A@B^T + bias.  EPI==1: scatter qkv (bias added, bf16).
template <int EPI>
__global__ __launch_bounds__(256) void gemm_bt64(
    const bf16* __restrict__ A,   // [M][K] bf16
    const bf16* __restrict__ Bt,  // [N][K] bf16
    const float* __restrict__ bias,  // [N] fp32
    float* __restrict__ Cf,          // EPI==0: [M][N] fp32
    bf16* __restrict__ qd, bf16* __restrict__ kd, bf16* __restrict__ vtd,
    int M, int N, int K) {
    // LDS tile: elem(row, k) at row*64 + ((k>>3)^(row&7))*8 + (k&7)
    __shared__ bf16 As[128 * 64];
    __shared__ bf16 Bs[128 * 64];
    const int t = threadIdx.x;
    const int lane = t & 63;
    const int lr = lane & 15, lg = lane >> 4;
    const int wave = t >> 6;
    const int wr = wave >> 1, wc = wave & 1;  // 2x2 waves of 64x64
    const int m0 = blockIdx.x * 128, n0 = blockIdx.y * 128;

    // staging: inst j covers LDS bytes j*4096 + t*16 -> row j*32 + (t>>3),
    // lds-chunk t&7; source chunk = (t&7) ^ (row&7)  (involution)
    const int sRow = t >> 3;
    const int sChunk = (t & 7) ^ (sRow & 7);
    const bf16* aSrc = A + (size_t)(m0 + sRow) * K + sChunk * 8;
    const bf16* bSrc = Bt + (size_t)(n0 + sRow) * K + sChunk * 8;
    const size_t rowStep32 = (size_t)32 * K;

    f32x4 acc[4][4] = {};

    for (int k0 = 0; k0 < K; k0 += 64) {
        __syncthreads();  // prev reads done (lgkm drained)
        #pragma unroll
        for (int j = 0; j < 4; ++j) {
            async16(aSrc + j * rowStep32 + k0, &As[j * 2048 + t * 8]);
            async16(bSrc + j * rowStep32 + k0, &Bs[j * 2048 + t * 8]);
        }
        __syncthreads();  // vmcnt drained -> tiles visible
        #pragma unroll
        for (int kh = 0; kh < 2; ++kh) {
            short8 af[4], bfr[4];
            #pragma unroll
            for (int i = 0; i < 4; ++i) {
                const int ar = wr * 64 + i * 16 + lr;
                af[i] = *reinterpret_cast<const short8*>(
                    &As[ar * 64 + ((kh * 4 + lg) ^ (ar & 7)) * 8]);
                const int br = wc * 64 + i * 16 + lr;
                bfr[i] = *reinterpret_cast<const short8*>(
                    &Bs[br * 64 + ((kh * 4 + lg) ^ (br & 7)) * 8]);
            }
            #pragma unroll
            for (int mi = 0; mi < 4; ++mi)
                #pragma unroll
                for (int ni = 0; ni < 4; ++ni)
                    acc[mi][ni] = __builtin_amdgcn_mfma_f32_16x16x32_bf16(
                        af[mi], bfr[ni], acc[mi][ni], 0, 0, 0);
        }
    }

    #pragma unroll
    for (int mi = 0; mi < 4; ++mi) {
        #pragma unroll
        for (int ni = 0; ni < 4; ++ni) {
            #pragma unroll
            for (int r = 0; r < 4; ++r) {
                const int row = m0 + wr * 64 + mi * 16 + lg * 4 + r;
                const int col = n0 + wc * 64 + ni * 16 + lr;
                const float v = acc[mi][ni][r] + bias[col];
                if constexpr (EPI == 0) {
                    Cf[(size_t)row * N + col] = v;
                } else {
                    const bf16 hv = __float2bfloat16(v);
                    const int part = col >> 10;      // 0=q 1=k 2=v
                    const int within = col & 1023;
                    const int h = within >> 6, d = within & 63;
                    const int b = row >> 11, s = row & 2047;
                    const int bh = b * 16 + h;
                    if (part == 0)
                        qd[((size_t)bh * 2048 + s) * 64 + d] = hv;
                    else if (part == 1)
                        kd[((size_t)bh * 2048 + s) * 64 + d] = hv;
                    else
                        vtd[((size_t)bh * 64 + d) * 2048 + s] = hv;
                }
            }
        }
    }
}

// ---------------- K4: causal flash attention (round-4 version) ---------------
__global__ __launch_bounds__(256, 2) void attn_kernel(const bf16* __restrict__ q,
                                                      const bf16* __restrict__ k,
                                                      const bf16* __restrict__ vt,
                                                      bf16* __restrict__ o) {
    const int S = 2048;
    const int f = blockIdx.x;
    const int res = f & 7, m = f >> 3;
    const int grp = m >> 4;
    const int bh = res + 8 * grp;
    const int bxr = m & 15;
    const int bx = (grp & 2) ? (15 - bxr) : bxr;
    const int b = bh >> 4, h = bh & 15;
    const int w = threadIdx.x >> 6;
    const int u = w >> 1, par = w & 1;
    const int lane = threadIdx.x & 63;
    const int ln = lane & 31;
    const int hi = lane >> 5;
    const int P = 2 * (15 - bx) + u;     // 0..31
    const int qbaseA = P * 64;
    const int qbaseB = P * 64 + 32;

    const bf16* qp = q + (size_t)bh * S * 64;
    const bf16* kp = k + (size_t)bh * S * 64;
    const bf16* vp = vt + (size_t)bh * 64 * S;

    short8 qfA[4], qfB[4];
    #pragma unroll
    for (int i = 0; i < 4; ++i) {
        qfA[i] = *reinterpret_cast<const short8*>(
            &qp[(size_t)(qbaseA + ln) * 64 + i * 16 + hi * 8]);
        qfB[i] = *reinterpret_cast<const short8*>(
            &qp[(size_t)(qbaseB + ln) * 64 + i * 16 + hi * 8]);
    }

    f32x16 oA0 = {}, oA1 = {}, oB0 = {}, oB1 = {};
    f32x4 lsvA = {0.f, 0.f, 0.f, 0.f}, lsvB = {0.f, 0.f, 0.f, 0.f};

    short8 kA[4], kB[4], vA[4], vB[4];

    auto kload = [&](short8 (&kf)[4], int tile) {
        const bf16* base = &kp[(size_t)(tile * 32 + ln) * 64 + hi * 8];
        #pragma unroll
        for (int i = 0; i < 4; ++i)
            kf[i] = *reinterpret_cast<const short8*>(base + i * 16);
    };
    auto vload = [&](short8 (&vf)[4], int tile) {
        #pragma unroll
        for (int dblk = 0; dblk < 2; ++dblk)
            #pragma unroll
            for (int half = 0; half < 2; ++half)
                vf[dblk * 2 + half] = *reinterpret_cast<const short8*>(
                    &vp[(size_t)(dblk * 32 + ln) * S + tile * 32 + half * 16 +
                        hi * 8]);
    };

    auto body = [&](const short8 (&kf)[4], const short8 (&vf)[4],
                    const short8 (&qf)[4], f32x16& o0, f32x16& o1, f32x4& lsv,
                    bool diag) {
        f32x16 z0 = {}, z1 = {};
        z0 = __builtin_amdgcn_mfma_f32_32x32x16_bf16(kf[0], qf[0], z0, 0, 0, 0);
        z0 = __builtin_amdgcn_mfma_f32_32x32x16_bf16(kf[1], qf[1], z0, 0, 0, 0);
        z1 = __builtin_amdgcn_mfma_f32_32x32x16_bf16(kf[2], qf[2], z1, 0, 0, 0);
        z1 = __builtin_amdgcn_mfma_f32_32x32x16_bf16(kf[3], qf[3], z1, 0, 0, 0);
        const f32x16 z = z0 + z1;
        f32x16 pv;
        #pragma unroll
        for (int r = 0; r < 16; ++r) {
            const int kreg = (r & 3) + 8 * (r >> 2) + 4 * hi;
            float e = __expf(z[r] * 0.125f);
            if (diag && (kreg > ln)) e = 0.f;
            pv[r] = e;
            lsv[r & 3] += e;
        }
        unsigned a0, a1, b0, b1, c0, c1, d0, d1;
        asm("v_cvt_pk_bf16_f32 %0, %1, %2" : "=v"(a0) : "v"(pv[0]), "v"(pv[1]));
        asm("v_cvt_pk_bf16_f32 %0, %1, %2" : "=v"(a1) : "v"(pv[2]), "v"(pv[3]));
        asm("v_cvt_pk_bf16_f32 %0, %1, %2" : "=v"(b0) : "v"(pv[4]), "v"(pv[5]));
        asm("v_cvt_pk_bf16_f32 %0, %1, %2" : "=v"(b1) : "v"(pv[6]), "v"(pv[7]));
        asm("v_cvt_pk_bf16_f32 %0, %1, %2" : "=v"(c0) : "v"(pv[8]), "v"(pv[9]));
        asm("v_cvt_pk_bf16_f32 %0, %1, %2" : "=v"(c1) : "v"(pv[10]), "v"(pv[11]));
        asm("v_cvt_pk_bf16_f32 %0, %1, %2" : "=v"(d0) : "v"(pv[12]), "v"(pv[13]));
        asm("v_cvt_pk_bf16_f32 %0, %1, %2" : "=v"(d1) : "v"(pv[14]), "v"(pv[15]));
        asm("v_permlane32_swap_b32 %0, %1" : "+v"(a0), "+v"(b0));
        asm("v_permlane32_swap_b32 %0, %1" : "+v"(a1), "+v"(b1));
        asm("v_permlane32_swap_b32 %0, %1" : "+v"(c0), "+v"(d0));
        asm("v_permlane32_swap_b32 %0, %1" : "+v"(c1), "+v"(d1));
        u32x4 t0, t1;
        t0[0] = a0; t0[1] = a1; t0[2] = b0; t0[3] = b1;   // P[q][kv 0..15]
        t1[0] = c0; t1[1] = c1; t1[2] = d0; t1[3] = d1;   // P[q][kv 16..31]
        const short8 pa0 = __builtin_bit_cast(short8, t0);
        const short8 pa1 = __builtin_bit_cast(short8, t1);
        o0 = __builtin_amdgcn_mfma_f32_32x32x16_bf16(pa0, vf[0], o0, 0, 0, 0);
        o0 = __builtin_amdgcn_mfma_f32_32x32x16_bf16(pa1, vf[1], o0, 0, 0, 0);
        o1 = __builtin_amdgcn_mfma_f32_32x32x16_bf16(pa0, vf[2], o1, 0, 0, 0);
        o1 = __builtin_amdgcn_mfma_f32_32x32x16_bf16(pa1, vf[3], o1, 0, 0, 0);
    };

    auto dual = [&](const short8 (&kf)[4], const short8 (&vf)[4]) {
        body(kf, vf, qfA, oA0, oA1, lsvA, false);
        body(kf, vf, qfB, oB0, oB1, lsvB, false);
    };
    auto final_body = [&](const short8 (&kf)[4], const short8 (&vf)[4]) {
        if (par == 0) {
            body(kf, vf, qfA, oA0, oA1, lsvA, true);
            body(kf, vf, qfB, oB0, oB1, lsvB, false);
        } else {
            body(kf, vf, qfB, oB0, oB1, lsvB, true);
        }
    };

    kload(kA, par);
    vload(vA, par);
    int i = 0;
    for (; i + 2 <= P; i += 2) {
        kload(kB, par + 2 * (i + 1));
        vload(vB, par + 2 * (i + 1));
        dual(kA, vA);
        kload(kA, par + 2 * (i + 2));
        vload(vA, par + 2 * (i + 2));
        dual(kB, vB);
    }
    if (i < P) {
        kload(kB, par + 2 * P);
        vload(vB, par + 2 * P);
        dual(kA, vA);
        final_body(kB, vB);
    } else {
        final_body(kA, vA);
    }

    float lsA = (lsvA[0] + lsvA[1]) + (lsvA[2] + lsvA[3]);
    float lsB = (lsvB[0] + lsvB[1]) + (lsvB[2] + lsvB[3]);

    __shared__ float red[2][64][65];
    __shared__ float redl[2][64][2];
    if (par == 1) {
        float* dst = red[u][lane];
        #pragma unroll
        for (int r = 0; r < 16; ++r) {
            dst[r] = oA0[r];
            dst[16 + r] = oA1[r];
            dst[32 + r] = oB0[r];
            dst[48 + r] = oB1[r];
        }
        redl[u][lane][0] = lsA;
        redl[u][lane][1] = lsB;
    }
    __syncthreads();
    if (par == 1) return;
    {
        const float* src = red[u][lane];
        #pragma unroll
        for (int r = 0; r < 16; ++r) {
            oA0[r] += src[r];
            oA1[r] += src[16 + r];
            oB0[r] += src[32 + r];
            oB1[r] += src[48 + r];
        }
        lsA += redl[u][lane][0];
        lsB += redl[u][lane][1];
    }

    lsA += __shfl_xor(lsA, 32, 64);
    lsB += __shfl_xor(lsB, 32, 64);
    const float myInvA = 1.0f / lsA;
    const float myInvB = 1.0f / lsB;
    #pragma unroll
    for (int r = 0; r < 16; ++r) {
        const int qrow = (r & 3) + 8 * (r >> 2) + 4 * hi;
        const float invA = __shfl(myInvA, qrow, 64);
        const float invB = __shfl(myInvB, qrow, 64);
        const size_t rowA = ((size_t)b * S + qbaseA + qrow) * 1024 + h * 64;
        const size_t rowB = ((size_t)b * S + qbaseB + qrow) * 1024 + h * 64;
        o[rowA + ln] = __float2bfloat16(oA0[r] * invA);
        o[rowA + 32 + ln] = __float2bfloat16(oA1[r] * invA);
        o[rowB + ln] = __float2bfloat16(oB0[r] * invB);
        o[rowB + 32 + ln] = __float2bfloat16(oB1[r] * invB);
    }
}

// -----------------------------------------------------------------------------
extern "C" void kernel_launch(void* const* d_in, const int* in_sizes, int n_in,
                              void* d_out, int out_size, void* d_ws, size_t ws_size,
                              hipStream_t stream) {
    const float* x = (const float*)d_in[0];     // [2,2048,1024]
    const float* Wqkv = (const float*)d_in[1];  // [1024,3072]
    const float* bqkv = (const float*)d_in[2];  // [3072]
    const float* Wo = (const float*)d_in[3];    // [1024,1024]
    const float* bo = (const float*)d_in[4];    // [1024]
    float* out = (float*)d_out;                 // [2,2048,1024] fp32
    char* ws = (char*)d_ws;

    // workspace layout (bytes), total 40 MB
    bf16* x_bf = (bf16*)(ws);                  //  8388608  [4096][1024]
    bf16* wqkv_t = (bf16*)(ws + 8388608);      //  6291456  [3072][1024]
    bf16* wo_t = (bf16*)(ws + 14680064);       //  2097152  [1024][1024]
    bf16* qb = (bf16*)(ws + 16777216);         //  8388608  [2,16,2048,64]
    bf16* kb = (bf16*)(ws + 25165824);         //  8388608  [2,16,2048,64]
    bf16* vtb = (bf16*)(ws + 33554432);        //  8388608  [2,16,64,2048]
    bf16* attn_o = x_bf;                       // alias: x_bf dead after gemm1

    cvt_kernel<<<4096, 256, 0, stream>>>(x, x_bf, 1048576);
    transpose_cvt<<<dim3(96, 32), dim3(32, 8), 0, stream>>>(Wqkv, wqkv_t, 1024, 3072);
    transpose_cvt<<<dim3(32, 32), dim3(32, 8), 0, stream>>>(Wo, wo_t, 1024, 1024);
    gemm_bt64<1><<<dim3(32, 24), 256, 0, stream>>>(x_bf, wqkv_t, bqkv, nullptr,
                                                   qb, kb, vtb, 4096, 3072, 1024);
    attn_kernel<<<512, 256, 0, stream>>>(qb, kb, vtb, attn_o);
    gemm_bt64<0><<<dim3(32, 8), 256, 0, stream>>>(attn_o, wo_t, bo, out, nullptr,
                                                  nullptr, nullptr, 4096, 1024, 1024);
}